// Round 16
// baseline (102.218 us; speedup 1.0000x reference)
//
#include <hip/hip_runtime.h>
#include <hip/hip_fp16.h>
#include <limits.h>

#define IN_DIM 128
#define OUT_DIM 64
#define NBUCK 782          // ceil(100000 / 128) row buckets
#define RPB 128            // rows per bucket
#define HRPB 64            // rows per gather half-bucket
#define CHUNK 2048         // edges per partition-role block (34KB LDS)
#define BCAP 4096          // fixed ecs slots per bucket (mean 2046)
#define SCAP2 2048         // max staged edges per half-bucket (mean ~1023)

// Payload packing: p.x = (rowlocal << 25) | (col << 7)
//  - col<<7 == byte offset of row in fp16 xw; gather addr = (p.x & 0x01FFFF80) | (q<<4)

typedef _Float16 half8_t __attribute__((ext_vector_type(8)));
typedef float    f32x4  __attribute__((ext_vector_type(4)));

__device__ __forceinline__ int kmap(int g, int j) {
    return g * 4 + (j & 3) + 16 * (j >> 2);   // g = lane>>4, j = elem 0..7
}

// ---------------------------------------------------------------------------
// Kernel 1: fused GEMM + partition, role-split by blockIdx parity so both
// phases overlap on every CU (they are data-independent).
//   GEMM role  (idx < ngb): 8 waves x 16 rows = 128 rows/block, MFMA f16.
//   PART role  (idx < npb): stage CHUNK edges, local hist+scan, reserve runs
//   in fixed bucket regions via cursor, coalesced flush.
// ---------------------------------------------------------------------------
__global__ __launch_bounds__(512) void fused_gemm_part_kernel(
    const float* __restrict__ x, const float* __restrict__ W,
    const float* __restrict__ b, __half* __restrict__ xw, int n_nodes, int ngb,
    const int* __restrict__ erow, const int* __restrict__ ecol,
    const float* __restrict__ eval_, int* __restrict__ cursor,
    int2* __restrict__ ecs, int n_edges, int npb) {
    __shared__ int  hist[NBUCK];
    __shared__ int  lbase[NBUCK];
    __shared__ int  gdelta[NBUCK];
    __shared__ int2 data[CHUNK];         // 16 KB
    __shared__ int  gpos[CHUNK];         // 8 KB
    __shared__ int  wsum[8];

    const int bid = blockIdx.x;
    const int nm  = min(ngb, npb);
    int role, idx;
    if (bid < 2 * nm) { role = bid & 1; idx = bid >> 1; }
    else              { idx = bid - nm; role = (ngb > nm) ? 0 : 1; }

    const int t = threadIdx.x;

    if (role == 0) {
        // ---------------- GEMM role ----------------
        const int l  = t & 63;
        const int wv = t >> 6;           // 0..7
        const int g  = l >> 4;
        const int rowbase = idx * 128 + wv * 16;
        const int row = rowbase + (l & 15);
        const bool rok = row < n_nodes;
        const float* xr = x + (size_t)row * IN_DIM;

        half8_t bf[4][4];
        #pragma unroll
        for (int n = 0; n < 4; ++n)
            #pragma unroll
            for (int ks = 0; ks < 4; ++ks) {
                half8_t a;
                #pragma unroll
                for (int j = 0; j < 8; ++j) {
                    const int k = ks * 32 + kmap(g, j);
                    a[j] = (_Float16)W[k * OUT_DIM + n * 16 + (l & 15)];
                }
                bf[n][ks] = a;
            }

        half8_t af[4];
        #pragma unroll
        for (int ks = 0; ks < 4; ++ks) {
            float4 c0 = rok ? *(const float4*)(xr + ks * 32 + g * 4)
                            : make_float4(0.f, 0.f, 0.f, 0.f);
            float4 c1 = rok ? *(const float4*)(xr + ks * 32 + 16 + g * 4)
                            : make_float4(0.f, 0.f, 0.f, 0.f);
            half8_t a;
            a[0] = (_Float16)c0.x; a[1] = (_Float16)c0.y;
            a[2] = (_Float16)c0.z; a[3] = (_Float16)c0.w;
            a[4] = (_Float16)c1.x; a[5] = (_Float16)c1.y;
            a[6] = (_Float16)c1.z; a[7] = (_Float16)c1.w;
            af[ks] = a;
        }

        f32x4 acc[4];
        #pragma unroll
        for (int n = 0; n < 4; ++n) acc[n] = (f32x4){0.f, 0.f, 0.f, 0.f};

        #pragma unroll
        for (int ks = 0; ks < 4; ++ks)
            #pragma unroll
            for (int n = 0; n < 4; ++n)
                acc[n] = __builtin_amdgcn_mfma_f32_16x16x32_f16(af[ks], bf[n][ks], acc[n], 0, 0, 0);

        float bias[4];
        #pragma unroll
        for (int n = 0; n < 4; ++n) bias[n] = b[n * 16 + (l & 15)];

        // C/D layout (m89-verified): col = lane&15, row = (lane>>4)*4 + reg
        #pragma unroll
        for (int n = 0; n < 4; ++n)
            #pragma unroll
            for (int q = 0; q < 4; ++q) {
                const int ro = rowbase + g * 4 + q;
                if (ro < n_nodes)
                    xw[(size_t)ro * OUT_DIM + n * 16 + (l & 15)] =
                        __float2half(acc[n][q] + bias[n]);
            }
    } else {
        // ---------------- partition role ----------------
        const int base = idx * CHUNK;
        const int cnt = min(CHUNK, n_edges - base);
        if (cnt <= 0) return;

        for (int i = t; i < NBUCK; i += 512) hist[i] = 0;
        __syncthreads();

        int   myrow[CHUNK / 512];
        int   mycol[CHUNK / 512];
        float myval[CHUNK / 512];
        #pragma unroll
        for (int i = 0; i < CHUNK / 512; ++i) {
            const int j = t + i * 512;
            if (j < cnt) {
                const int e = base + j;
                myrow[i] = erow[e];
                mycol[i] = ecol[e];
                myval[i] = eval_[e];
                atomicAdd(&hist[myrow[i] >> 7], 1);
            }
        }
        __syncthreads();

        // local exclusive scan of hist -> lbase
        {
            const int i0 = 2 * t, i1 = 2 * t + 1;
            const int v0 = (i0 < NBUCK) ? hist[i0] : 0;
            const int v1 = (i1 < NBUCK) ? hist[i1] : 0;
            const int s2 = v0 + v1;
            int inc = s2;
            #pragma unroll
            for (int d = 1; d < 64; d <<= 1) {
                int u = __shfl_up(inc, d, 64);
                if ((t & 63) >= d) inc += u;
            }
            if ((t & 63) == 63) wsum[t >> 6] = inc;
            __syncthreads();
            int wp = 0;
            #pragma unroll
            for (int w = 0; w < 8; ++w) if (w < (t >> 6)) wp += wsum[w];
            const int ex = wp + (inc - s2);
            if (i0 < NBUCK) lbase[i0] = ex;
            if (i1 < NBUCK) lbase[i1] = ex + v0;
        }
        __syncthreads();

        // reserve runs in fixed bucket regions
        for (int i = t; i < NBUCK; i += 512) {
            const int c = hist[i];
            gdelta[i] = c ? (i * BCAP + atomicAdd(&cursor[i], c) - lbase[i]) : 0;
        }
        __syncthreads();

        #pragma unroll
        for (int i = 0; i < CHUNK / 512; ++i) {
            const int j = t + i * 512;
            if (j < cnt) {
                const int bk = myrow[i] >> 7;
                const int slot = atomicAdd(&lbase[bk], 1);
                int2 p;
                p.x = (int)(((unsigned)(myrow[i] & (RPB - 1)) << 25) |
                            ((unsigned)mycol[i] << 7));
                p.y = __float_as_int(myval[i]);
                data[slot] = p;
                gpos[slot] = slot + gdelta[bk];
            }
        }
        __syncthreads();

        const int limit = NBUCK * BCAP - 1;
        for (int slot = t; slot < cnt; slot += 512)
            ecs[min(gpos[slot], limit)] = data[slot];   // clamp = memory safety only
    }
}

// ---------------------------------------------------------------------------
// Kernel 2: fused in-half-bucket sort + gather + ReLU (round-15 form).
// ---------------------------------------------------------------------------
__global__ __launch_bounds__(512) void bucket_gather_kernel(
    const __half* __restrict__ xw, const int2* __restrict__ ecs,
    const int* __restrict__ cursor, float* __restrict__ out,
    int n_nodes) {
    __shared__ int2 data[SCAP2];         // 16 KB
    __shared__ int  hist[HRPB];
    __shared__ int  rstart[HRPB + 1];

    const int bk2  = blockIdx.x;
    const int bk   = bk2 >> 1;
    const int half = bk2 & 1;
    const int t    = threadIdx.x;
    const int lane = t & 63;
    const int wv   = t >> 6;             // 0..7
    const int q    = lane & 7;           // channel octet
    const int g    = lane >> 3;          // edge subgroup 0..7

    const int s   = bk * BCAP;
    const int cnt = min(cursor[bk], BCAP);
    const int e   = s + cnt;
    const int rowbase = bk * RPB + half * HRPB;
    const char* xwb = (const char*)xw;

    if (t < HRPB) hist[t] = 0;
    __syncthreads();

    // pass 1: filtered histogram of this half's rows
    for (int i = t; i < cnt; i += 512) {
        const unsigned rl = ((unsigned)ecs[s + i].x) >> 25;
        if ((int)(rl >> 6) == half) atomicAdd(&hist[rl & (HRPB - 1)], 1);
    }
    __syncthreads();

    // scan hist[64] -> rstart (single wave)
    if (t < HRPB) {
        const int v = hist[t];
        int inc = v;
        #pragma unroll
        for (int d = 1; d < 64; d <<= 1) {
            int u = __shfl_up(inc, d, 64);
            if (t >= d) inc += u;
        }
        rstart[t] = inc - v;
        hist[t]   = inc - v;             // running cursor
        if (t == HRPB - 1) rstart[HRPB] = inc;
    }
    __syncthreads();

    const int cntH = rstart[HRPB];

    if (cntH <= SCAP2) {
        // pass 2: filtered scatter into LDS in row-sorted order
        for (int i = t; i < cnt; i += 512) {
            const int2 p = ecs[s + i];
            const unsigned rl = ((unsigned)p.x) >> 25;
            if ((int)(rl >> 6) == half) {
                const int pos = atomicAdd(&hist[rl & (HRPB - 1)], 1);
                data[pos] = p;
            }
        }
        __syncthreads();

        // gather: wave wv owns local rows [wv*8, wv*8+8), 2 at a time
        for (int rp = 0; rp < 4; ++rp) {
            const int rl0 = wv * 8 + rp * 2;
            const int rl1 = rl0 + 1;
            int j0 = rstart[rl0];
            const int e0 = rstart[rl0 + 1];
            int j1 = rstart[rl1];
            const int e1 = rstart[rl1 + 1];

            float acc0[8], acc1[8];
            #pragma unroll
            for (int i = 0; i < 8; ++i) { acc0[i] = 0.f; acc1[i] = 0.f; }

            while (j0 < e0 || j1 < e1) {
                const bool a0 = j0 < e0;
                const bool a1 = j1 < e1;
                float v0 = 0.f, v1 = 0.f;
                unsigned off0 = 0, off1 = 0;
                if (a0) {
                    const int ei = j0 + g;
                    const int2 p = data[min(ei, cntH - 1)];
                    v0 = (ei < e0) ? __int_as_float(p.y) : 0.f;
                    off0 = (((unsigned)p.x) & 0x01FFFF80u) | ((unsigned)q << 4);
                }
                if (a1) {
                    const int ei = j1 + g;
                    const int2 p = data[min(ei, cntH - 1)];
                    v1 = (ei < e1) ? __int_as_float(p.y) : 0.f;
                    off1 = (((unsigned)p.x) & 0x01FFFF80u) | ((unsigned)q << 4);
                }
                union { uint4 u; __half2 h[4]; } U0, U1;
                if (a0) U0.u = *(const uint4*)(xwb + off0);
                if (a1) U1.u = *(const uint4*)(xwb + off1);
                if (a0) {
                    #pragma unroll
                    for (int i = 0; i < 4; ++i) {
                        const float2 f = __half22float2(U0.h[i]);
                        acc0[2 * i]     = fmaf(v0, f.x, acc0[2 * i]);
                        acc0[2 * i + 1] = fmaf(v0, f.y, acc0[2 * i + 1]);
                    }
                    j0 += 8;
                }
                if (a1) {
                    #pragma unroll
                    for (int i = 0; i < 4; ++i) {
                        const float2 f = __half22float2(U1.h[i]);
                        acc1[2 * i]     = fmaf(v1, f.x, acc1[2 * i]);
                        acc1[2 * i + 1] = fmaf(v1, f.y, acc1[2 * i + 1]);
                    }
                    j1 += 8;
                }
            }

            #pragma unroll
            for (int d = 8; d < 64; d <<= 1) {
                #pragma unroll
                for (int i = 0; i < 8; ++i) {
                    acc0[i] += __shfl_xor(acc0[i], d, 64);
                    acc1[i] += __shfl_xor(acc1[i], d, 64);
                }
            }

            if (g == 0) {
                const int r0 = rowbase + rl0;
                const int r1 = rowbase + rl1;
                if (r0 < n_nodes) {
                    float4 o0, o1;
                    o0.x = fmaxf(acc0[0], 0.f); o0.y = fmaxf(acc0[1], 0.f);
                    o0.z = fmaxf(acc0[2], 0.f); o0.w = fmaxf(acc0[3], 0.f);
                    o1.x = fmaxf(acc0[4], 0.f); o1.y = fmaxf(acc0[5], 0.f);
                    o1.z = fmaxf(acc0[6], 0.f); o1.w = fmaxf(acc0[7], 0.f);
                    float* op = out + (size_t)r0 * OUT_DIM + q * 8;
                    *(float4*)(op)     = o0;
                    *(float4*)(op + 4) = o1;
                }
                if (r1 < n_nodes) {
                    float4 o0, o1;
                    o0.x = fmaxf(acc1[0], 0.f); o0.y = fmaxf(acc1[1], 0.f);
                    o0.z = fmaxf(acc1[2], 0.f); o0.w = fmaxf(acc1[3], 0.f);
                    o1.x = fmaxf(acc1[4], 0.f); o1.y = fmaxf(acc1[5], 0.f);
                    o1.z = fmaxf(acc1[6], 0.f); o1.w = fmaxf(acc1[7], 0.f);
                    float* op = out + (size_t)r1 * OUT_DIM + q * 8;
                    *(float4*)(op)     = o0;
                    *(float4*)(op + 4) = o1;
                }
            }
        }
    } else {
        // overflow (cntH > SCAP2, ~never): global filter-scan; edge subgroup
        // g takes edges ≡ g (mod 8) so the fold sums disjoint subsets.
        for (int rr = 0; rr < 8; ++rr) {
            const int r = rowbase + wv * 8 + rr;
            if (r >= n_nodes) break;
            float acc[8];
            #pragma unroll
            for (int i = 0; i < 8; ++i) acc[i] = 0.f;
            const unsigned rl = (unsigned)(r & (RPB - 1));
            for (int j = s + g; j < e; j += 8) {
                const int2 p = ecs[j];
                if ((((unsigned)p.x) >> 25) == rl) {
                    const float v = __int_as_float(p.y);
                    const unsigned off = (((unsigned)p.x) & 0x01FFFF80u) | ((unsigned)q << 4);
                    union { uint4 u; __half2 h[4]; } U;
                    U.u = *(const uint4*)(xwb + off);
                    #pragma unroll
                    for (int i = 0; i < 4; ++i) {
                        const float2 f = __half22float2(U.h[i]);
                        acc[2 * i]     = fmaf(v, f.x, acc[2 * i]);
                        acc[2 * i + 1] = fmaf(v, f.y, acc[2 * i + 1]);
                    }
                }
            }
            #pragma unroll
            for (int d = 8; d < 64; d <<= 1)
                #pragma unroll
                for (int i = 0; i < 8; ++i)
                    acc[i] += __shfl_xor(acc[i], d, 64);
            if (g == 0) {
                float4 o0, o1;
                o0.x = fmaxf(acc[0], 0.f); o0.y = fmaxf(acc[1], 0.f);
                o0.z = fmaxf(acc[2], 0.f); o0.w = fmaxf(acc[3], 0.f);
                o1.x = fmaxf(acc[4], 0.f); o1.y = fmaxf(acc[5], 0.f);
                o1.z = fmaxf(acc[6], 0.f); o1.w = fmaxf(acc[7], 0.f);
                float* op = out + (size_t)r * OUT_DIM + q * 8;
                *(float4*)(op)     = o0;
                *(float4*)(op + 4) = o1;
            }
        }
    }
}

// ---------------------------------------------------------------------------
// Fallback: atomic scatter path.
// ---------------------------------------------------------------------------
__global__ __launch_bounds__(256) void edge_scatter_kernel(
    const __half* __restrict__ xw, const int* __restrict__ erow,
    const int* __restrict__ ecol, const float* __restrict__ eval_,
    float* __restrict__ out, int n_edges) {
    const int lane  = threadIdx.x & 63;
    const int wid   = (blockIdx.x * blockDim.x + threadIdx.x) >> 6;
    const int nwave = (gridDim.x * blockDim.x) >> 6;
    for (int e = wid; e < n_edges; e += nwave) {
        const float m = eval_[e] * __half2float(xw[(size_t)ecol[e] * OUT_DIM + lane]);
        atomicAdd(&out[(size_t)erow[e] * OUT_DIM + lane], m);
    }
}

__global__ __launch_bounds__(256) void relu_kernel(float4* __restrict__ p, int n4) {
    const int stride = gridDim.x * blockDim.x;
    for (int i = blockIdx.x * blockDim.x + threadIdx.x; i < n4; i += stride) {
        float4 v = p[i];
        v.x = fmaxf(v.x, 0.f); v.y = fmaxf(v.y, 0.f);
        v.z = fmaxf(v.z, 0.f); v.w = fmaxf(v.w, 0.f);
        p[i] = v;
    }
}

extern "C" void kernel_launch(void* const* d_in, const int* in_sizes, int n_in,
                              void* d_out, int out_size, void* d_ws, size_t ws_size,
                              hipStream_t stream) {
    const float* x     = (const float*)d_in[0];
    const int*   erow  = (const int*)d_in[1];
    const int*   ecol  = (const int*)d_in[2];
    const float* eval_ = (const float*)d_in[3];
    const float* W     = (const float*)d_in[4];
    const float* b     = (const float*)d_in[5];
    float*       out   = (float*)d_out;

    const int n_nodes = in_sizes[0] / IN_DIM;
    const int n_edges = in_sizes[1];

    auto align256 = [](size_t v) { return (v + 255) & ~(size_t)255; };
    size_t off_xw     = 0;
    size_t off_cursor = align256(off_xw     + (size_t)n_nodes * OUT_DIM * 2); // fp16 xw
    size_t off_ecs    = align256(off_cursor + (size_t)NBUCK * 4);
    size_t need       = off_ecs + (size_t)NBUCK * BCAP * 8;

    __half* xw = (__half*)((char*)d_ws + off_xw);

    const int ngb = (n_nodes + 127) / 128;   // gemm-role blocks

    const bool main_path = (need <= ws_size) && (n_nodes <= NBUCK * RPB) && (n_edges > 0);

    if (main_path) {
        int*  cursor = (int*)((char*)d_ws + off_cursor);
        int2* ecs    = (int2*)((char*)d_ws + off_ecs);
        const int npb = (n_edges + CHUNK - 1) / CHUNK;   // partition-role blocks

        hipMemsetAsync(cursor, 0, (size_t)NBUCK * 4, stream);
        fused_gemm_part_kernel<<<ngb + npb, 512, 0, stream>>>(
            x, W, b, xw, n_nodes, ngb,
            erow, ecol, eval_, cursor, ecs, n_edges, npb);
        bucket_gather_kernel<<<NBUCK * 2, 512, 0, stream>>>(
            xw, ecs, cursor, out, n_nodes);
    } else {
        fused_gemm_part_kernel<<<ngb, 512, 0, stream>>>(
            x, W, b, xw, n_nodes, ngb,
            nullptr, nullptr, nullptr, nullptr, nullptr, 0, 0);
        hipMemsetAsync(d_out, 0, (size_t)out_size * sizeof(float), stream);
        edge_scatter_kernel<<<8192, 256, 0, stream>>>(xw, erow, ecol, eval_, out, n_edges);
        relu_kernel<<<2048, 256, 0, stream>>>((float4*)d_out, out_size / 4);
    }
}

// Round 17
// 101.324 us; speedup vs baseline: 1.0088x; 1.0088x over previous
//
#include <hip/hip_runtime.h>
#include <hip/hip_fp16.h>
#include <limits.h>

#define IN_DIM 128
#define OUT_DIM 64
#define NBUCK 782          // ceil(100000 / 128) row buckets
#define RPB 128            // rows per bucket
#define HRPB 64            // rows per gather half-bucket
#define CHUNK 4096         // edges per partition block
#define BCAP 4096          // fixed ecs slots per bucket (mean 2046, 45-sigma headroom)
#define SCAP2 2048         // max staged edges per half-bucket (mean ~1023)

// Payload packing: p.x = (rowlocal << 25) | (col << 7)
//  - col<<7 == byte offset of row in fp16 xw; gather addr = (p.x & 0x01FFFF80) | (q<<4)

typedef _Float16 half8_t __attribute__((ext_vector_type(8)));
typedef float    f32x4  __attribute__((ext_vector_type(4)));

__device__ __forceinline__ int kmap(int g, int j) {
    return g * 4 + (j & 3) + 16 * (j >> 2);   // g = lane>>4, j = elem 0..7
}

// ---------------------------------------------------------------------------
// Kernel 1: xw = fp16(x @ W + b) via MFMA 16x16x32 f16. W fragments loaded
// per-lane directly from the 32KB L1/L2-hot W. (Round-16 lesson: fusing this
// with partition unions LDS+VGPR across roles and strangles both.)
// ---------------------------------------------------------------------------
__global__ __launch_bounds__(256) void gemm_kernel(
    const float* __restrict__ x, const float* __restrict__ W,
    const float* __restrict__ b, __half* __restrict__ xw, int n_nodes) {
    const int t  = threadIdx.x;
    const int l  = t & 63;
    const int wv = t >> 6;
    const int g  = l >> 4;
    const int rowbase = blockIdx.x * 64 + wv * 16;
    const int row = rowbase + (l & 15);
    const bool rok = row < n_nodes;
    const float* xr = x + (size_t)row * IN_DIM;

    // B fragments straight from W: bf[n][ks][j] = W[ks*32+kmap(g,j)][n*16+(l&15)]
    half8_t bf[4][4];
    #pragma unroll
    for (int n = 0; n < 4; ++n)
        #pragma unroll
        for (int ks = 0; ks < 4; ++ks) {
            half8_t a;
            #pragma unroll
            for (int j = 0; j < 8; ++j) {
                const int k = ks * 32 + kmap(g, j);
                a[j] = (_Float16)W[k * OUT_DIM + n * 16 + (l & 15)];
            }
            bf[n][ks] = a;
        }

    half8_t af[4];
    #pragma unroll
    for (int ks = 0; ks < 4; ++ks) {
        float4 c0 = rok ? *(const float4*)(xr + ks * 32 + g * 4)
                        : make_float4(0.f, 0.f, 0.f, 0.f);
        float4 c1 = rok ? *(const float4*)(xr + ks * 32 + 16 + g * 4)
                        : make_float4(0.f, 0.f, 0.f, 0.f);
        half8_t a;
        a[0] = (_Float16)c0.x; a[1] = (_Float16)c0.y;
        a[2] = (_Float16)c0.z; a[3] = (_Float16)c0.w;
        a[4] = (_Float16)c1.x; a[5] = (_Float16)c1.y;
        a[6] = (_Float16)c1.z; a[7] = (_Float16)c1.w;
        af[ks] = a;
    }

    f32x4 acc[4];
    #pragma unroll
    for (int n = 0; n < 4; ++n) acc[n] = (f32x4){0.f, 0.f, 0.f, 0.f};

    #pragma unroll
    for (int ks = 0; ks < 4; ++ks)
        #pragma unroll
        for (int n = 0; n < 4; ++n)
            acc[n] = __builtin_amdgcn_mfma_f32_16x16x32_f16(af[ks], bf[n][ks], acc[n], 0, 0, 0);

    float bias[4];
    #pragma unroll
    for (int n = 0; n < 4; ++n) bias[n] = b[n * 16 + (l & 15)];

    // C/D layout (m89-verified): col = lane&15, row = (lane>>4)*4 + reg
    #pragma unroll
    for (int n = 0; n < 4; ++n)
        #pragma unroll
        for (int q = 0; q < 4; ++q) {
            const int ro = rowbase + g * 4 + q;
            if (ro < n_nodes)
                xw[(size_t)ro * OUT_DIM + n * 16 + (l & 15)] =
                    __float2half(acc[n][q] + bias[n]);
        }
}

// ---------------------------------------------------------------------------
// Kernel 2: partition edges into fixed-capacity bucket regions of ecs.
// Bucket bk owns slots [bk*BCAP, bk*BCAP + cursor[bk]); no scan anywhere.
// ---------------------------------------------------------------------------
__global__ __launch_bounds__(512) void partition_kernel(
    const int* __restrict__ erow, const int* __restrict__ ecol,
    const float* __restrict__ eval_, int* __restrict__ cursor,
    int2* __restrict__ ecs, int n_edges) {
    __shared__ int  hist[NBUCK];
    __shared__ int  lbase[NBUCK];
    __shared__ int  gdelta[NBUCK];
    __shared__ int2 data[CHUNK];
    __shared__ int  gpos[CHUNK];
    __shared__ int  wsum[8];

    const int t = threadIdx.x;
    const int base = blockIdx.x * CHUNK;
    const int cnt = min(CHUNK, n_edges - base);

    for (int i = t; i < NBUCK; i += 512) hist[i] = 0;
    __syncthreads();

    int   myrow[CHUNK / 512];
    int   mycol[CHUNK / 512];
    float myval[CHUNK / 512];
    #pragma unroll
    for (int i = 0; i < CHUNK / 512; ++i) {
        const int idx = t + i * 512;
        if (idx < cnt) {
            const int e = base + idx;
            myrow[i] = erow[e];
            mycol[i] = ecol[e];
            myval[i] = eval_[e];
            atomicAdd(&hist[myrow[i] >> 7], 1);
        }
    }
    __syncthreads();

    // scan of local hist -> lbase (local exclusive prefix within the chunk)
    {
        const int i0 = 2 * t, i1 = 2 * t + 1;
        const int v0 = (i0 < NBUCK) ? hist[i0] : 0;
        const int v1 = (i1 < NBUCK) ? hist[i1] : 0;
        const int s2 = v0 + v1;
        int inc = s2;
        #pragma unroll
        for (int d = 1; d < 64; d <<= 1) {
            int u = __shfl_up(inc, d, 64);
            if ((t & 63) >= d) inc += u;
        }
        if ((t & 63) == 63) wsum[t >> 6] = inc;
        __syncthreads();
        int wp = 0;
        #pragma unroll
        for (int w = 0; w < 8; ++w) if (w < (t >> 6)) wp += wsum[w];
        const int ex = wp + (inc - s2);
        if (i0 < NBUCK) lbase[i0] = ex;
        if (i1 < NBUCK) lbase[i1] = ex + v0;
    }
    __syncthreads();

    // reserve runs in fixed bucket regions
    for (int i = t; i < NBUCK; i += 512) {
        const int c = hist[i];
        gdelta[i] = c ? (i * BCAP + atomicAdd(&cursor[i], c) - lbase[i]) : 0;
    }
    __syncthreads();

    #pragma unroll
    for (int i = 0; i < CHUNK / 512; ++i) {
        const int idx = t + i * 512;
        if (idx < cnt) {
            const int bk = myrow[i] >> 7;
            const int slot = atomicAdd(&lbase[bk], 1);
            int2 p;
            p.x = (int)(((unsigned)(myrow[i] & (RPB - 1)) << 25) |
                        ((unsigned)mycol[i] << 7));
            p.y = __float_as_int(myval[i]);
            data[slot] = p;
            gpos[slot] = slot + gdelta[bk];
        }
    }
    __syncthreads();

    const int limit = NBUCK * BCAP - 1;
    for (int slot = t; slot < cnt; slot += 512)
        ecs[min(gpos[slot], limit)] = data[slot];   // clamp = memory safety only
}

// ---------------------------------------------------------------------------
// Kernel 3: fused in-half-bucket sort + gather + ReLU. TWO blocks per bucket
// (grid = 2*NBUCK, 512 thr = 8 waves): block bk2 handles rows
// [half*64, half*64+64) of bucket bk2>>1. Filter-stages its half of the
// run into LDS row-sorted (run L2-warm from partition), then each wave
// gathers 8 rows (2 at a time, paired latency chains, 8 edges per vmem).
// ---------------------------------------------------------------------------
__global__ __launch_bounds__(512) void bucket_gather_kernel(
    const __half* __restrict__ xw, const int2* __restrict__ ecs,
    const int* __restrict__ cursor, float* __restrict__ out,
    int n_nodes) {
    __shared__ int2 data[SCAP2];         // 16 KB
    __shared__ int  hist[HRPB];
    __shared__ int  rstart[HRPB + 1];

    const int bk2  = blockIdx.x;
    const int bk   = bk2 >> 1;
    const int half = bk2 & 1;
    const int t    = threadIdx.x;
    const int lane = t & 63;
    const int wv   = t >> 6;             // 0..7
    const int q    = lane & 7;           // channel octet
    const int g    = lane >> 3;          // edge subgroup 0..7

    const int s   = bk * BCAP;
    const int cnt = min(cursor[bk], BCAP);
    const int e   = s + cnt;
    const int rowbase = bk * RPB + half * HRPB;
    const char* xwb = (const char*)xw;

    if (t < HRPB) hist[t] = 0;
    __syncthreads();

    // pass 1: filtered histogram of this half's rows
    for (int i = t; i < cnt; i += 512) {
        const unsigned rl = ((unsigned)ecs[s + i].x) >> 25;
        if ((int)(rl >> 6) == half) atomicAdd(&hist[rl & (HRPB - 1)], 1);
    }
    __syncthreads();

    // scan hist[64] -> rstart (single wave)
    if (t < HRPB) {
        const int v = hist[t];
        int inc = v;
        #pragma unroll
        for (int d = 1; d < 64; d <<= 1) {
            int u = __shfl_up(inc, d, 64);
            if (t >= d) inc += u;
        }
        rstart[t] = inc - v;
        hist[t]   = inc - v;             // running cursor
        if (t == HRPB - 1) rstart[HRPB] = inc;
    }
    __syncthreads();

    const int cntH = rstart[HRPB];

    if (cntH <= SCAP2) {
        // pass 2: filtered scatter into LDS in row-sorted order
        for (int i = t; i < cnt; i += 512) {
            const int2 p = ecs[s + i];
            const unsigned rl = ((unsigned)p.x) >> 25;
            if ((int)(rl >> 6) == half) {
                const int pos = atomicAdd(&hist[rl & (HRPB - 1)], 1);
                data[pos] = p;
            }
        }
        __syncthreads();

        // gather: wave wv owns local rows [wv*8, wv*8+8), 2 at a time
        for (int rp = 0; rp < 4; ++rp) {
            const int rl0 = wv * 8 + rp * 2;
            const int rl1 = rl0 + 1;
            int j0 = rstart[rl0];
            const int e0 = rstart[rl0 + 1];
            int j1 = rstart[rl1];
            const int e1 = rstart[rl1 + 1];

            float acc0[8], acc1[8];
            #pragma unroll
            for (int i = 0; i < 8; ++i) { acc0[i] = 0.f; acc1[i] = 0.f; }

            while (j0 < e0 || j1 < e1) {
                const bool a0 = j0 < e0;
                const bool a1 = j1 < e1;
                float v0 = 0.f, v1 = 0.f;
                unsigned off0 = 0, off1 = 0;
                if (a0) {
                    const int ei = j0 + g;
                    const int2 p = data[min(ei, cntH - 1)];
                    v0 = (ei < e0) ? __int_as_float(p.y) : 0.f;
                    off0 = (((unsigned)p.x) & 0x01FFFF80u) | ((unsigned)q << 4);
                }
                if (a1) {
                    const int ei = j1 + g;
                    const int2 p = data[min(ei, cntH - 1)];
                    v1 = (ei < e1) ? __int_as_float(p.y) : 0.f;
                    off1 = (((unsigned)p.x) & 0x01FFFF80u) | ((unsigned)q << 4);
                }
                union { uint4 u; __half2 h[4]; } U0, U1;
                if (a0) U0.u = *(const uint4*)(xwb + off0);
                if (a1) U1.u = *(const uint4*)(xwb + off1);
                if (a0) {
                    #pragma unroll
                    for (int i = 0; i < 4; ++i) {
                        const float2 f = __half22float2(U0.h[i]);
                        acc0[2 * i]     = fmaf(v0, f.x, acc0[2 * i]);
                        acc0[2 * i + 1] = fmaf(v0, f.y, acc0[2 * i + 1]);
                    }
                    j0 += 8;
                }
                if (a1) {
                    #pragma unroll
                    for (int i = 0; i < 4; ++i) {
                        const float2 f = __half22float2(U1.h[i]);
                        acc1[2 * i]     = fmaf(v1, f.x, acc1[2 * i]);
                        acc1[2 * i + 1] = fmaf(v1, f.y, acc1[2 * i + 1]);
                    }
                    j1 += 8;
                }
            }

            #pragma unroll
            for (int d = 8; d < 64; d <<= 1) {
                #pragma unroll
                for (int i = 0; i < 8; ++i) {
                    acc0[i] += __shfl_xor(acc0[i], d, 64);
                    acc1[i] += __shfl_xor(acc1[i], d, 64);
                }
            }

            if (g == 0) {
                const int r0 = rowbase + rl0;
                const int r1 = rowbase + rl1;
                if (r0 < n_nodes) {
                    float4 o0, o1;
                    o0.x = fmaxf(acc0[0], 0.f); o0.y = fmaxf(acc0[1], 0.f);
                    o0.z = fmaxf(acc0[2], 0.f); o0.w = fmaxf(acc0[3], 0.f);
                    o1.x = fmaxf(acc0[4], 0.f); o1.y = fmaxf(acc0[5], 0.f);
                    o1.z = fmaxf(acc0[6], 0.f); o1.w = fmaxf(acc0[7], 0.f);
                    float* op = out + (size_t)r0 * OUT_DIM + q * 8;
                    *(float4*)(op)     = o0;
                    *(float4*)(op + 4) = o1;
                }
                if (r1 < n_nodes) {
                    float4 o0, o1;
                    o0.x = fmaxf(acc1[0], 0.f); o0.y = fmaxf(acc1[1], 0.f);
                    o0.z = fmaxf(acc1[2], 0.f); o0.w = fmaxf(acc1[3], 0.f);
                    o1.x = fmaxf(acc1[4], 0.f); o1.y = fmaxf(acc1[5], 0.f);
                    o1.z = fmaxf(acc1[6], 0.f); o1.w = fmaxf(acc1[7], 0.f);
                    float* op = out + (size_t)r1 * OUT_DIM + q * 8;
                    *(float4*)(op)     = o0;
                    *(float4*)(op + 4) = o1;
                }
            }
        }
    } else {
        // overflow (cntH > SCAP2, ~never): global filter-scan; edge subgroup
        // g takes edges ≡ g (mod 8) so the fold sums disjoint subsets.
        for (int rr = 0; rr < 8; ++rr) {
            const int r = rowbase + wv * 8 + rr;
            if (r >= n_nodes) break;
            float acc[8];
            #pragma unroll
            for (int i = 0; i < 8; ++i) acc[i] = 0.f;
            const unsigned rl = (unsigned)(r & (RPB - 1));
            for (int j = s + g; j < e; j += 8) {
                const int2 p = ecs[j];
                if ((((unsigned)p.x) >> 25) == rl) {
                    const float v = __int_as_float(p.y);
                    const unsigned off = (((unsigned)p.x) & 0x01FFFF80u) | ((unsigned)q << 4);
                    union { uint4 u; __half2 h[4]; } U;
                    U.u = *(const uint4*)(xwb + off);
                    #pragma unroll
                    for (int i = 0; i < 4; ++i) {
                        const float2 f = __half22float2(U.h[i]);
                        acc[2 * i]     = fmaf(v, f.x, acc[2 * i]);
                        acc[2 * i + 1] = fmaf(v, f.y, acc[2 * i + 1]);
                    }
                }
            }
            #pragma unroll
            for (int d = 8; d < 64; d <<= 1)
                #pragma unroll
                for (int i = 0; i < 8; ++i)
                    acc[i] += __shfl_xor(acc[i], d, 64);
            if (g == 0) {
                float4 o0, o1;
                o0.x = fmaxf(acc[0], 0.f); o0.y = fmaxf(acc[1], 0.f);
                o0.z = fmaxf(acc[2], 0.f); o0.w = fmaxf(acc[3], 0.f);
                o1.x = fmaxf(acc[4], 0.f); o1.y = fmaxf(acc[5], 0.f);
                o1.z = fmaxf(acc[6], 0.f); o1.w = fmaxf(acc[7], 0.f);
                float* op = out + (size_t)r * OUT_DIM + q * 8;
                *(float4*)(op)     = o0;
                *(float4*)(op + 4) = o1;
            }
        }
    }
}

// ---------------------------------------------------------------------------
// Fallback: atomic scatter path.
// ---------------------------------------------------------------------------
__global__ __launch_bounds__(256) void edge_scatter_kernel(
    const __half* __restrict__ xw, const int* __restrict__ erow,
    const int* __restrict__ ecol, const float* __restrict__ eval_,
    float* __restrict__ out, int n_edges) {
    const int lane  = threadIdx.x & 63;
    const int wid   = (blockIdx.x * blockDim.x + threadIdx.x) >> 6;
    const int nwave = (gridDim.x * blockDim.x) >> 6;
    for (int e = wid; e < n_edges; e += nwave) {
        const float m = eval_[e] * __half2float(xw[(size_t)ecol[e] * OUT_DIM + lane]);
        atomicAdd(&out[(size_t)erow[e] * OUT_DIM + lane], m);
    }
}

__global__ __launch_bounds__(256) void relu_kernel(float4* __restrict__ p, int n4) {
    const int stride = gridDim.x * blockDim.x;
    for (int i = blockIdx.x * blockDim.x + threadIdx.x; i < n4; i += stride) {
        float4 v = p[i];
        v.x = fmaxf(v.x, 0.f); v.y = fmaxf(v.y, 0.f);
        v.z = fmaxf(v.z, 0.f); v.w = fmaxf(v.w, 0.f);
        p[i] = v;
    }
}

extern "C" void kernel_launch(void* const* d_in, const int* in_sizes, int n_in,
                              void* d_out, int out_size, void* d_ws, size_t ws_size,
                              hipStream_t stream) {
    const float* x     = (const float*)d_in[0];
    const int*   erow  = (const int*)d_in[1];
    const int*   ecol  = (const int*)d_in[2];
    const float* eval_ = (const float*)d_in[3];
    const float* W     = (const float*)d_in[4];
    const float* b     = (const float*)d_in[5];
    float*       out   = (float*)d_out;

    const int n_nodes = in_sizes[0] / IN_DIM;
    const int n_edges = in_sizes[1];

    auto align256 = [](size_t v) { return (v + 255) & ~(size_t)255; };
    size_t off_xw     = 0;
    size_t off_cursor = align256(off_xw     + (size_t)n_nodes * OUT_DIM * 2); // fp16 xw
    size_t off_ecs    = align256(off_cursor + (size_t)NBUCK * 4);
    size_t need       = off_ecs + (size_t)NBUCK * BCAP * 8;

    __half* xw = (__half*)((char*)d_ws + off_xw);

    const bool main_path = (need <= ws_size) && (n_nodes <= NBUCK * RPB) && (n_edges > 0);

    if (main_path) {
        int*  cursor = (int*)((char*)d_ws + off_cursor);
        int2* ecs    = (int2*)((char*)d_ws + off_ecs);

        hipMemsetAsync(cursor, 0, (size_t)NBUCK * 4, stream);
        gemm_kernel<<<(n_nodes + 63) / 64, 256, 0, stream>>>(x, W, b, xw, n_nodes);
        partition_kernel<<<(n_edges + CHUNK - 1) / CHUNK, 512, 0, stream>>>(
            erow, ecol, eval_, cursor, ecs, n_edges);
        bucket_gather_kernel<<<NBUCK * 2, 512, 0, stream>>>(
            xw, ecs, cursor, out, n_nodes);
    } else {
        gemm_kernel<<<(n_nodes + 63) / 64, 256, 0, stream>>>(x, W, b, xw, n_nodes);
        hipMemsetAsync(d_out, 0, (size_t)out_size * sizeof(float), stream);
        edge_scatter_kernel<<<8192, 256, 0, stream>>>(xw, erow, ecol, eval_, out, n_edges);
        relu_kernel<<<2048, 256, 0, stream>>>((float4*)d_out, out_size / 4);
    }
}